// Round 1
// baseline (307.769 us; speedup 1.0000x reference)
//
#include <hip/hip_runtime.h>
#include <hip/hip_bf16.h>
#include <stdint.h>

// ObjectDetectionLoss (SSD MultiBox) — MI355X / gfx950
// B=64, N=16800, C=21. Output: 3 fp32 scalars (loss_total, log_bboxs, log_labels).

#define NB 64
#define NN 16800
#define NC 21

__device__ __constant__ float c_SCALE_XY = 10.0f;
__device__ __constant__ float c_SCALE_WH = 5.0f;
#define FP32_EPS_F 1.1920928955078125e-07f

// ---------------- workspace layout (bytes) ----------------
// [0,    512)  double loss_bboxs[64]   (atomic accum, zeroed)
// [512, 1024)  double ce_pos[64]       (atomic accum, zeroed)
// [1024,1536)  double ce_topk[64]      (written by k_topk)
// [1536,1792)  int    pos_num[64]      (atomic accum, zeroed)
// [2048, 2048+4*NB*NN) float ce_neg[NB*NN]

// ===================== Kernel 1: per-anchor =====================
__global__ __launch_bounds__(256) void k_perdata(
    const float* __restrict__ p_bboxs, const float* __restrict__ g_bboxs,
    const float* __restrict__ p_labels, const int* __restrict__ g_labels,
    const float* __restrict__ ancs,
    float* __restrict__ ce_neg, double* __restrict__ loss_bboxs,
    double* __restrict__ ce_pos, int* __restrict__ pos_num)
{
    __shared__ float lab[256 * NC];            // 21504 B
    const int tid = threadIdx.x;
    const int base = blockIdx.x * 256;

    // ---- stage p_labels tile: 256 anchors * 21 floats, fully coalesced float4 ----
    {
        const float4* src = (const float4*)(p_labels + (size_t)base * NC); // 21504*blk bytes, 16B aligned
        float4* dst = (float4*)lab;
        constexpr int NV = 256 * NC / 4;       // 1344
        for (int j = tid; j < NV; j += 256) dst[j] = src[j];
    }
    __syncthreads();

    const int idx = base + tid;                // < NB*NN = 1,075,200 (grid exact)
    const int b = idx / NN;
    const int n = idx - b * NN;

    const float4 p = ((const float4*)p_bboxs)[idx];
    const float4 g = ((const float4*)g_bboxs)[idx];
    const float4 a = ((const float4*)ancs)[n];
    const int gl = g_labels[idx];

    // regression targets + SmoothL1 (beta=1), summed over 4 coords
    const float tx = c_SCALE_XY * (g.x - a.x) / a.z;
    const float ty = c_SCALE_XY * (g.y - a.y) / a.w;
    const float tw = c_SCALE_WH * logf(g.z / a.z);
    const float th = c_SCALE_WH * logf(g.w / a.w);
    float sl1 = 0.f;
    {
        float d, ad;
        d = p.x - tx; ad = fabsf(d); sl1 += (ad < 1.f) ? 0.5f * d * d : ad - 0.5f;
        d = p.y - ty; ad = fabsf(d); sl1 += (ad < 1.f) ? 0.5f * d * d : ad - 0.5f;
        d = p.z - tw; ad = fabsf(d); sl1 += (ad < 1.f) ? 0.5f * d * d : ad - 0.5f;
        d = p.w - th; ad = fabsf(d); sl1 += (ad < 1.f) ? 0.5f * d * d : ad - 0.5f;
    }

    // cross entropy: lse - x[gl]
    const float* row = lab + tid * NC;         // stride 21 (odd) -> 2-way LDS alias, free
    float m = row[0];
    #pragma unroll
    for (int c = 1; c < NC; ++c) m = fmaxf(m, row[c]);
    float s = 0.f;
    #pragma unroll
    for (int c = 0; c < NC; ++c) s += expf(row[c] - m);
    const float lse = m + logf(s);
    const float ce = fmaxf(lse - row[gl], 0.f);   // clamp >=0 (bit-monotonic for select)

    const bool pos = gl > 0;
    ce_neg[idx] = pos ? 0.f : ce;              // coalesced store

    // ---- per-wave segmented reduce (a wave spans at most 2 batches) ----
    const int lane = tid & 63;
    const int bL0  = __shfl(b, 0);
    const int bL63 = __shfl(b, 63);

    {
        float rs = (pos && b == bL0) ? sl1 : 0.f;
        float rc = (pos && b == bL0) ? ce  : 0.f;
        int   rn = (pos && b == bL0) ? 1   : 0;
        #pragma unroll
        for (int off = 32; off > 0; off >>= 1) {
            rs += __shfl_down(rs, off);
            rc += __shfl_down(rc, off);
            rn += __shfl_down(rn, off);
        }
        if (lane == 0 && rn > 0) {
            atomicAdd(&pos_num[bL0], rn);
            atomicAdd(&loss_bboxs[bL0], (double)rs);
            atomicAdd(&ce_pos[bL0], (double)rc);
        }
    }
    if (bL63 != bL0) {
        float rs = (pos && b == bL63) ? sl1 : 0.f;
        float rc = (pos && b == bL63) ? ce  : 0.f;
        int   rn = (pos && b == bL63) ? 1   : 0;
        #pragma unroll
        for (int off = 32; off > 0; off >>= 1) {
            rs += __shfl_down(rs, off);
            rc += __shfl_down(rc, off);
            rn += __shfl_down(rn, off);
        }
        if (lane == 0 && rn > 0) {
            atomicAdd(&pos_num[bL63], rn);
            atomicAdd(&loss_bboxs[bL63], (double)rs);
            atomicAdd(&ce_pos[bL63], (double)rc);
        }
    }
}

// ===================== Kernel 2: per-batch top-k sum via LDS radix-select =====================
// Exact k-th-largest by IEEE-bit radix select; sum = sum(bits > T) + r*T is
// value-exact regardless of tie-breaking (ties contribute equal values).
__global__ __launch_bounds__(256) void k_topk(
    const float* __restrict__ ce_neg, const int* __restrict__ pos_num,
    double* __restrict__ ce_topk)
{
    __shared__ uint32_t vals[NN];              // 67200 B
    __shared__ uint32_t hist[256];
    __shared__ uint32_t sh_prefix;
    __shared__ int      sh_rem;
    __shared__ double   sh_part[4];

    const int tid = threadIdx.x;
    const int lane = tid & 63;
    const int b = blockIdx.x;
    const float* src = ce_neg + (size_t)b * NN;

    for (int i = tid; i < NN; i += 256) vals[i] = __float_as_uint(src[i]);

    int k0 = pos_num[b] * 3;                   // NEG_RATIO
    if (k0 > NN) k0 = NN;
    const int k = (k0 > 0) ? k0 : 1;           // run machinery with k>=1; mask at end
    if (tid == 0) { sh_rem = k; sh_prefix = 0u; }
    __syncthreads();

    constexpr int ITERS = (NN + 255) / 256;    // 66

    for (int pass = 0; pass < 4; ++pass) {
        const int shift = 24 - pass * 8;
        hist[tid] = 0u;
        const uint32_t prefix = sh_prefix;
        __syncthreads();

        if (pass == 0) {
            // exponent byte clusters in ~5 bins -> aggregate per-wave via ballot
            for (int it = 0; it < ITERS; ++it) {
                const int i = tid + it * 256;
                const bool valid = i < NN;
                const uint32_t d = valid ? (vals[i] >> 24) : 0u;
                unsigned long long active = __ballot(valid);
                while (active) {
                    const int leader = __ffsll((long long)active) - 1;
                    const uint32_t dl = __shfl(d, leader);
                    const unsigned long long same = __ballot(valid && d == dl) & active;
                    if (lane == leader) atomicAdd(&hist[dl], (uint32_t)__popcll(same));
                    active &= ~same;
                }
            }
        } else {
            for (int it = 0; it < ITERS; ++it) {
                const int i = tid + it * 256;
                if (i < NN) {
                    const uint32_t v = vals[i];
                    if ((v >> (shift + 8)) == prefix)
                        atomicAdd(&hist[(v >> shift) & 0xFFu], 1u);
                }
            }
        }
        __syncthreads();

        if (tid == 0) {
            int r = sh_rem;
            int dsel = 0;
            for (int bin = 255; bin >= 0; --bin) {
                const int c = (int)hist[bin];
                if (r > c) r -= c;
                else { dsel = bin; break; }    // invariant r <= matching-count ensures break
            }
            sh_rem = r;
            sh_prefix = (prefix << 8) | (uint32_t)dsel;
        }
        __syncthreads();
    }

    const uint32_t T = sh_prefix;              // exact k-th largest bit pattern
    const int r = sh_rem;                      // how many values == T to include

    double local = 0.0;
    for (int i = tid; i < NN; i += 256) {
        const uint32_t v = vals[i];
        if (v > T) local += (double)__uint_as_float(v);
    }
    #pragma unroll
    for (int off = 32; off > 0; off >>= 1) local += __shfl_down(local, off);
    if (lane == 0) sh_part[tid >> 6] = local;
    __syncthreads();
    if (tid == 0) {
        double tot = sh_part[0] + sh_part[1] + sh_part[2] + sh_part[3];
        tot += (double)r * (double)__uint_as_float(T);
        ce_topk[b] = (k0 > 0) ? tot : 0.0;
    }
}

// ===================== Kernel 3: final reduction over B =====================
__global__ __launch_bounds__(64) void k_final(
    const double* __restrict__ loss_bboxs, const double* __restrict__ ce_pos,
    const double* __restrict__ ce_topk, const int* __restrict__ pos_num,
    float* __restrict__ out)
{
    const int t = threadIdx.x;                 // 64 == NB
    const double lb = loss_bboxs[t];
    const double ll = ce_pos[t] + ce_topk[t];
    const int pn = pos_num[t];
    const double nm = (pn > 0) ? 1.0 : 0.0;
    const float pf = fmaxf((float)pn, FP32_EPS_F);
    const double inv = nm / (double)pf;
    double tb = lb * inv;
    double tl = ll * inv;
    double tt = tb + tl;                        // COEFF = (1,1)
    #pragma unroll
    for (int off = 32; off > 0; off >>= 1) {
        tt += __shfl_down(tt, off);
        tb += __shfl_down(tb, off);
        tl += __shfl_down(tl, off);
    }
    if (t == 0) {
        out[0] = (float)(tt / (double)NB);
        out[1] = (float)(tb / (double)NB);
        out[2] = (float)(tl / (double)NB);
    }
}

// ===================== launcher =====================
extern "C" void kernel_launch(void* const* d_in, const int* in_sizes, int n_in,
                              void* d_out, int out_size, void* d_ws, size_t ws_size,
                              hipStream_t stream)
{
    const float* p_bboxs  = (const float*)d_in[0];
    const float* g_bboxs  = (const float*)d_in[1];
    const float* p_labels = (const float*)d_in[2];
    const int*   g_labels = (const int*)d_in[3];
    const float* ancs     = (const float*)d_in[4];
    float* out = (float*)d_out;

    char* ws = (char*)d_ws;
    double* loss_bboxs = (double*)(ws);
    double* ce_pos     = (double*)(ws + 512);
    double* ce_topk    = (double*)(ws + 1024);
    int*    pos_num    = (int*)(ws + 1536);
    float*  ce_neg     = (float*)(ws + 2048);

    // zero the atomic accumulators (ws is poisoned 0xAA before every launch)
    hipMemsetAsync(ws, 0, 2048, stream);

    k_perdata<<<(NB * NN) / 256, 256, 0, stream>>>(
        p_bboxs, g_bboxs, p_labels, g_labels, ancs,
        ce_neg, loss_bboxs, ce_pos, pos_num);

    k_topk<<<NB, 256, 0, stream>>>(ce_neg, pos_num, ce_topk);

    k_final<<<1, 64, 0, stream>>>(loss_bboxs, ce_pos, ce_topk, pos_num, out);
}